// Round 8
// baseline (97.306 us; speedup 1.0000x reference)
//
#include <hip/hip_runtime.h>
#include <cstddef>

// Shapes: B=4, H=W=D=16, C=32, N=4096, Dout=13; out (4,16,16,13,32) f32.

typedef float f32x4 __attribute__((ext_vector_type(4)));
typedef short s16x8 __attribute__((ext_vector_type(8)));

#define SQRT_LOG2E 1.2011224087864498f   // sqrt(log2(e)); xb scaled so QK^T is exp2-domain
#define C2SHIFT    57.70780163555854f    // 40*log2(e)

// RNE f32->bf16 pack of two floats into one u32 (low = first arg). Proven R1-R5.
__device__ inline unsigned pk2(float a, float b) {
  union { float f; unsigned u; } ca, cb;
  ca.f = a; cb.f = b;
  unsigned ra = (ca.u + 0x7fffu + ((ca.u >> 16) & 1u)) >> 16;
  unsigned rb = (cb.u + 0x7fffu + ((cb.u >> 16) & 1u)) >> 16;
  return ra | (rb << 16);
}
__device__ inline float ubf(ushort u) {
  union { unsigned u; float f; } c; c.u = ((unsigned)u) << 16; return c.f;
}

// ---------------------------------------------------------------------------
// Prep: xb = bf16(x * sqrt(log2e)) row-major [b][n][32]  (QK^T operands only);
// xtf = X^T MFMA A-fragment tiles (UNSCALED, used as PV values + Gram):
// per (b, ktile, c-half h): lane l holds X^T[16h+(l&15)][ktile*32+8*(l>>4)+j].
// ---------------------------------------------------------------------------
__global__ __launch_bounds__(256) void k_prep(
    const float* __restrict__ x, ushort* __restrict__ xb, ushort* __restrict__ xtf)
{
  int t = blockIdx.x * 256 + threadIdx.x;          // 0..65535
  const float4* xs = (const float4*)x;
  float4 v0 = xs[2 * t], v1 = xs[2 * t + 1];
  uint4 o;
  o.x = pk2(v0.x * SQRT_LOG2E, v0.y * SQRT_LOG2E);
  o.y = pk2(v0.z * SQRT_LOG2E, v0.w * SQRT_LOG2E);
  o.z = pk2(v1.x * SQRT_LOG2E, v1.y * SQRT_LOG2E);
  o.w = pk2(v1.z * SQRT_LOG2E, v1.w * SQRT_LOG2E);
  ((uint4*)xb)[t] = o;

  int b = t >> 14, r2 = t & 16383;
  int ktile = r2 >> 7, r3 = r2 & 127;
  int h = r3 >> 6, lane = r3 & 63;
  int g = lane >> 4, c = h * 16 + (lane & 15);
  const float* src = x + (((size_t)b * 4096 + ktile * 32 + 8 * g) * 32 + c);
  float w[8];
#pragma unroll
  for (int j = 0; j < 8; ++j) w[j] = src[(size_t)j * 32];
  uint4 u;
  u.x = pk2(w[0], w[1]); u.y = pk2(w[2], w[3]);
  u.z = pk2(w[4], w[5]); u.w = pk2(w[6], w[7]);
  ((uint4*)xtf)[(size_t)((b * 128 + ktile) * 2 + h) * 64 + lane] = u;
}

// ---------------------------------------------------------------------------
// Merged Gram + per-batch algebra. grid = 4 blocks (b) x 1024 thr (16 waves).
// Stage A: each wave MFMAs 8 ktiles of G=X^T X and s=X^T 1; LDS float-atomic
// reduce (commutative -> ULP-level nondet only). Stage B: energy2 -> softmax
// -> M,m -> folded conv weights w2[b][kd][i][f], b2[b][f].
// ---------------------------------------------------------------------------
__global__ __launch_bounds__(1024) void k_tiny2(
    const ushort* __restrict__ xtf,
    const float* __restrict__ wq, const float* __restrict__ bq,
    const float* __restrict__ wk, const float* __restrict__ bk,
    const float* __restrict__ wv, const float* __restrict__ bv,
    const float* __restrict__ gamma,
    const float* __restrict__ wpos, const float* __restrict__ bpos,
    float* __restrict__ w2, float* __restrict__ b2)
{
  __shared__ float G[1024], s[32], t1[1024], att[1024], M[1024], mvec[32];
  int b = blockIdx.x, tid = threadIdx.x;
  int wid = tid >> 6, lane = tid & 63;
  G[tid] = 0.f;
  if (tid < 32) s[tid] = 0.f;
  __syncthreads();

  // Stage A: Gram via MFMA
  const ushort* xtb = xtf + (size_t)b * 131072;    // 256*512
  f32x4 z = {0.f, 0.f, 0.f, 0.f};
  f32x4 G00 = z, G01 = z, G10 = z, G11 = z, s0 = z, s1 = z;
  s16x8 ones;
#pragma unroll
  for (int j = 0; j < 8; ++j) ones[j] = (short)0x3F80;
  for (int t = wid * 8; t < wid * 8 + 8; ++t) {
    const ushort* xt = xtb + (size_t)t * 1024 + lane * 8;
    s16x8 a0 = *(const s16x8*)(xt);
    s16x8 a1 = *(const s16x8*)(xt + 512);
    G00 = __builtin_amdgcn_mfma_f32_16x16x32_bf16(a0, a0, G00, 0, 0, 0);
    G01 = __builtin_amdgcn_mfma_f32_16x16x32_bf16(a0, a1, G01, 0, 0, 0);
    G10 = __builtin_amdgcn_mfma_f32_16x16x32_bf16(a1, a0, G10, 0, 0, 0);
    G11 = __builtin_amdgcn_mfma_f32_16x16x32_bf16(a1, a1, G11, 0, 0, 0);
    s0  = __builtin_amdgcn_mfma_f32_16x16x32_bf16(a0, ones, s0, 0, 0, 0);
    s1  = __builtin_amdgcn_mfma_f32_16x16x32_bf16(a1, ones, s1, 0, 0, 0);
  }
  int g = lane >> 4, c16 = lane & 15;
#pragma unroll
  for (int hr = 0; hr < 2; ++hr)
#pragma unroll
    for (int hc = 0; hc < 2; ++hc) {
      f32x4 v = hr ? (hc ? G11 : G10) : (hc ? G01 : G00);
#pragma unroll
      for (int r = 0; r < 4; ++r)
        atomicAdd(&G[(16 * hr + 4 * g + r) * 32 + 16 * hc + c16], v[r]);
    }
  if (c16 == 0) {
#pragma unroll
    for (int hr = 0; hr < 2; ++hr) {
      f32x4 v = hr ? s1 : s0;
#pragma unroll
      for (int r = 0; r < 4; ++r) atomicAdd(&s[16 * hr + 4 * g + r], v[r]);
    }
  }
  __syncthreads();

  // Stage B: algebra (tid = (c,f))
  int c = tid >> 5, f = tid & 31;
  float t = 0.f;
  for (int j = 0; j < 32; ++j) t = fmaf(G[c * 32 + j], wk[j * 32 + f], t);
  t1[tid] = t;
  __syncthreads();
  float swk = 0.f, swq = 0.f;
  for (int j = 0; j < 32; ++j) {
    swk = fmaf(s[j], wk[j * 32 + f], swk);
    swq = fmaf(s[j], wq[j * 32 + c], swq);
  }
  float e = 0.f;
  for (int i = 0; i < 32; ++i) e = fmaf(wq[i * 32 + c], t1[i * 32 + f], e);
  e += bq[c] * (swk + 4096.f * bk[f]) + swq * bk[f];
  float m_ = e;
  for (int off = 16; off; off >>= 1) m_ = fmaxf(m_, __shfl_xor(m_, off, 32));
  float p = __expf(e - m_);
  float sum = p;
  for (int off = 16; off; off >>= 1) sum += __shfl_xor(sum, off, 32);
  att[tid] = p / sum;                              // att[c][f]
  __syncthreads();
  float mm = 0.f;
  for (int j = 0; j < 32; ++j) mm = fmaf(wv[c * 32 + j], att[f * 32 + j], mm);
  M[c * 32 + f] = mm;
  if (c == 0) {
    float mv = 0.f;
    for (int j = 0; j < 32; ++j) mv = fmaf(bv[j], att[f * 32 + j], mv);
    mvec[f] = mv;
  }
  __syncthreads();
  float gam = gamma[0];
  for (int kd = 0; kd < 4; ++kd) {
    float acc = 0.f;
    for (int j = 0; j < 32; ++j)
      acc = fmaf(M[c * 32 + j], wpos[(kd * 32 + j) * 32 + f], acc);
    w2[((b * 4 + kd) * 32 + c) * 32 + f] = gam * acc + wpos[(kd * 32 + c) * 32 + f];
  }
  if (c == 0) {
    float acc = 0.f;
    for (int kd = 0; kd < 4; ++kd)
      for (int j = 0; j < 32; ++j)
        acc = fmaf(mvec[j], wpos[(kd * 32 + j) * 32 + f], acc);
    b2[b * 32 + f] = gam * acc + bpos[f];
  }
}

// ---------------------------------------------------------------------------
// MFMA flash attention partials — register-only P path (key-row permutation),
// exp2 domain (xb pre-scaled), shift folded into MFMA C-operand, manual RNE
// packing (pk2), l accumulated via ones-MFMA (matrix pipe, not VALU).
// grid = 128*KS blocks x 256 thr (4 waves, 32 q-rows each).
// ---------------------------------------------------------------------------
__global__ __launch_bounds__(256) void k_flash2(
    const ushort* __restrict__ xb, const ushort* __restrict__ xtf,
    ushort* __restrict__ acct, float* __restrict__ lpart, int KS)
{
  int bs = blockIdx.x;
  int ks = bs % KS, t2 = bs / KS;
  int b = t2 >> 5, qb = t2 & 31;
  int wid = threadIdx.x >> 6, lane = threadIdx.x & 63;
  int g = lane >> 4, c16 = lane & 15;
  int qw = qb * 128 + wid * 32;
  const ushort* xbb = xb + ((size_t)b << 17);

  s16x8 qA = *(const s16x8*)(xbb + (qw + c16) * 32 + 8 * g);
  s16x8 qB = *(const s16x8*)(xbb + (qw + 16 + c16) * 32 + 8 * g);
  f32x4 z = {0.f, 0.f, 0.f, 0.f};
  f32x4 minit = {-C2SHIFT, -C2SHIFT, -C2SHIFT, -C2SHIFT};
  f32x4 oA0 = z, oA1 = z, oB0 = z, oB1 = z, lacA = z, lacB = z;
  s16x8 ones;
#pragma unroll
  for (int j = 0; j < 8; ++j) ones[j] = (short)0x3F80;
  int nk = 4096 / KS, k00 = ks * nk;
  const ushort* xtb = xtf + (size_t)b * 131072;
  int kap = ((c16 >> 2) << 3) + (c16 & 3);         // kappa(c16)

  for (int kt = 0; kt < nk; kt += 32) {
    int k0 = k00 + kt;
    const ushort* kr = xbb + (size_t)k0 * 32;
    s16x8 kf0 = *(const s16x8*)(kr + (size_t)kap * 32 + 8 * g);
    s16x8 kf1 = *(const s16x8*)(kr + (size_t)(kap + 4) * 32 + 8 * g);
    const ushort* xt = xtb + (size_t)(k0 >> 5) * 1024 + lane * 8;
    s16x8 a0 = *(const s16x8*)(xt);
    s16x8 a1 = *(const s16x8*)(xt + 512);

    // energies arrive pre-shifted: e' = log2e*(q.k) - 40*log2e
    f32x4 eA0 = __builtin_amdgcn_mfma_f32_16x16x32_bf16(kf0, qA, minit, 0, 0, 0);
    f32x4 eA1 = __builtin_amdgcn_mfma_f32_16x16x32_bf16(kf1, qA, minit, 0, 0, 0);
    f32x4 eB0 = __builtin_amdgcn_mfma_f32_16x16x32_bf16(kf0, qB, minit, 0, 0, 0);
    f32x4 eB1 = __builtin_amdgcn_mfma_f32_16x16x32_bf16(kf1, qB, minit, 0, 0, 0);

    f32x4 pA0, pA1, pB0, pB1;
#pragma unroll
    for (int r = 0; r < 4; ++r) {
      pA0[r] = __builtin_amdgcn_exp2f(eA0[r]);
      pA1[r] = __builtin_amdgcn_exp2f(eA1[r]);
      pB0[r] = __builtin_amdgcn_exp2f(eB0[r]);
      pB1[r] = __builtin_amdgcn_exp2f(eB1[r]);
    }
    uint4 uA = make_uint4(pk2(pA0[0], pA0[1]), pk2(pA0[2], pA0[3]),
                          pk2(pA1[0], pA1[1]), pk2(pA1[2], pA1[3]));
    uint4 uB = make_uint4(pk2(pB0[0], pB0[1]), pk2(pB0[2], pB0[3]),
                          pk2(pB1[0], pB1[1]), pk2(pB1[2], pB1[3]));
    s16x8 fpA = __builtin_bit_cast(s16x8, uA);
    s16x8 fpB = __builtin_bit_cast(s16x8, uB);

    oA0 = __builtin_amdgcn_mfma_f32_16x16x32_bf16(a0, fpA, oA0, 0, 0, 0);
    oA1 = __builtin_amdgcn_mfma_f32_16x16x32_bf16(a1, fpA, oA1, 0, 0, 0);
    oB0 = __builtin_amdgcn_mfma_f32_16x16x32_bf16(a0, fpB, oB0, 0, 0, 0);
    oB1 = __builtin_amdgcn_mfma_f32_16x16x32_bf16(a1, fpB, oB1, 0, 0, 0);
    // l[q] via ones-row MFMA: every D row = sum_k P[k][q]
    lacA = __builtin_amdgcn_mfma_f32_16x16x32_bf16(ones, fpA, lacA, 0, 0, 0);
    lacB = __builtin_amdgcn_mfma_f32_16x16x32_bf16(ones, fpB, lacB, 0, 0, 0);
  }

  size_t pbi = (size_t)(ks * 4 + b);
  if (g == 0) {
    lpart[pbi * 4096 + qw + c16] = lacA[0];
    lpart[pbi * 4096 + qw + 16 + c16] = lacB[0];
  }
  ushort* ab = acct + pbi * 131072;                // [n][c] bf16
#pragma unroll
  for (int h = 0; h < 2; ++h) {
    f32x4 vA = h ? oA1 : oA0;
    f32x4 vB = h ? oB1 : oB0;
    *(uint2*)(ab + (size_t)(qw + c16) * 32 + 16 * h + 4 * g) =
        make_uint2(pk2(vA[0], vA[1]), pk2(vA[2], vA[3]));
    *(uint2*)(ab + (size_t)(qw + 16 + c16) * 32 + 16 * h + 4 * g) =
        make_uint2(pk2(vB[0], vB[1]), pk2(vB[2], vB[3]));
  }
}

// ---------------------------------------------------------------------------
// Fused combine + conv: ca kept in LDS (bf16), both conv branches + relu + sum.
// grid (16 hwg, 4 b) x 256 thr.
// ---------------------------------------------------------------------------
__global__ __launch_bounds__(256) void k_cc(
    const ushort* __restrict__ acct, const float* __restrict__ lpart,
    const float* __restrict__ x, const float* __restrict__ beta,
    const float* __restrict__ wch, const float* __restrict__ bch,
    const float* __restrict__ w2, const float* __restrict__ b2,
    float* __restrict__ out, int KS)
{
  __shared__ ushort caS[256][34];
  __shared__ float4 wcS[1024], wpS[1024];
  __shared__ float bcS[32], bpS[32];
  int hwg = blockIdx.x, b = blockIdx.y, tid = threadIdx.x;
  const float4* wsrc = (const float4*)wch;
  const float4* psrc = (const float4*)(w2 + (size_t)b * 4096);
  for (int i = tid; i < 1024; i += 256) { wcS[i] = wsrc[i]; wpS[i] = psrc[i]; }
  if (tid < 32) { bcS[tid] = bch[tid]; bpS[tid] = b2[b * 32 + tid]; }

  // phase 1: combine KS attnout partials -> ca row (bf16 in LDS)
  int n = hwg * 256 + tid;
  float L = 0.f;
  for (int s = 0; s < KS; ++s) L += lpart[(size_t)(s * 4 + b) * 4096 + n];
  float sc = beta[0] / L;
  float a[32];
#pragma unroll
  for (int c = 0; c < 32; ++c) a[c] = 0.f;
  for (int s = 0; s < KS; ++s) {
    const uint4* ab4 = (const uint4*)(acct + (size_t)(s * 4 + b) * 131072 + (size_t)n * 32);
#pragma unroll
    for (int j2 = 0; j2 < 4; ++j2) {
      uint4 v = ab4[j2];
      a[8 * j2 + 0] += ubf((ushort)(v.x & 0xffffu));
      a[8 * j2 + 1] += ubf((ushort)(v.x >> 16));
      a[8 * j2 + 2] += ubf((ushort)(v.y & 0xffffu));
      a[8 * j2 + 3] += ubf((ushort)(v.y >> 16));
      a[8 * j2 + 4] += ubf((ushort)(v.z & 0xffffu));
      a[8 * j2 + 5] += ubf((ushort)(v.z >> 16));
      a[8 * j2 + 6] += ubf((ushort)(v.w & 0xffffu));
      a[8 * j2 + 7] += ubf((ushort)(v.w >> 16));
    }
  }
  const float* xr = x + ((size_t)b * 4096 + n) * 32;
#pragma unroll
  for (int c2 = 0; c2 < 16; ++c2) {
    float r0 = fmaf(sc, a[2 * c2 + 0], xr[2 * c2 + 0]);
    float r1 = fmaf(sc, a[2 * c2 + 1], xr[2 * c2 + 1]);
    *(unsigned*)(&caS[tid][2 * c2]) = pk2(r0, r1);
  }
  __syncthreads();

  // phase 2: conv3d(1,1,4) + relu on both branches, sum. 208 active threads.
  if (tid < 208) {
    int hw_l = tid / 13, dout = tid % 13;
    int rbase = hw_l * 16 + dout;
    size_t xrow = ((size_t)b * 4096 + (size_t)(hwg * 16 + hw_l) * 16 + dout) * 32;
    float accC[32], accP[32];
#pragma unroll
    for (int f = 0; f < 32; ++f) { accC[f] = bcS[f]; accP[f] = bpS[f]; }
    for (int kd = 0; kd < 4; ++kd) {
      const float4* xr4 = (const float4*)(x + xrow + (size_t)kd * 32);
#pragma unroll
      for (int c4 = 0; c4 < 8; ++c4) {
        float4 xv = xr4[c4];
#pragma unroll
        for (int e = 0; e < 4; ++e) {
          float xve = (e == 0 ? xv.x : e == 1 ? xv.y : e == 2 ? xv.z : xv.w);
          float cve = ubf(caS[rbase + kd][4 * c4 + e]);
          int c = 4 * c4 + e;
          int wbase = (kd * 32 + c) * 8;
#pragma unroll
          for (int f4 = 0; f4 < 8; ++f4) {
            float4 w1 = wcS[wbase + f4];
            accC[4*f4+0] = fmaf(cve, w1.x, accC[4*f4+0]);
            accC[4*f4+1] = fmaf(cve, w1.y, accC[4*f4+1]);
            accC[4*f4+2] = fmaf(cve, w1.z, accC[4*f4+2]);
            accC[4*f4+3] = fmaf(cve, w1.w, accC[4*f4+3]);
            float4 wv = wpS[wbase + f4];
            accP[4*f4+0] = fmaf(xve, wv.x, accP[4*f4+0]);
            accP[4*f4+1] = fmaf(xve, wv.y, accP[4*f4+1]);
            accP[4*f4+2] = fmaf(xve, wv.z, accP[4*f4+2]);
            accP[4*f4+3] = fmaf(xve, wv.w, accP[4*f4+3]);
          }
        }
      }
    }
    int gid = b * 3328 + (hwg * 16 + hw_l) * 13 + dout;
    float4* orow = (float4*)(out + (size_t)gid * 32);
#pragma unroll
    for (int f4 = 0; f4 < 8; ++f4) {
      float4 o;
      o.x = fmaxf(accC[4*f4+0], 0.f) + fmaxf(accP[4*f4+0], 0.f);
      o.y = fmaxf(accC[4*f4+1], 0.f) + fmaxf(accP[4*f4+1], 0.f);
      o.z = fmaxf(accC[4*f4+2], 0.f) + fmaxf(accP[4*f4+2], 0.f);
      o.w = fmaxf(accC[4*f4+3], 0.f) + fmaxf(accP[4*f4+3], 0.f);
      orow[f4] = o;
    }
  }
}

extern "C" void kernel_launch(void* const* d_in, const int* in_sizes, int n_in,
                              void* d_out, int out_size, void* d_ws, size_t ws_size,
                              hipStream_t stream)
{
  const float* x     = (const float*)d_in[0];
  const float* beta  = (const float*)d_in[1];
  const float* wq    = (const float*)d_in[2];
  const float* bq    = (const float*)d_in[3];
  const float* wk    = (const float*)d_in[4];
  const float* bk    = (const float*)d_in[5];
  const float* wv    = (const float*)d_in[6];
  const float* bv    = (const float*)d_in[7];
  const float* gamma = (const float*)d_in[8];
  const float* wch   = (const float*)d_in[9];
  const float* bch   = (const float*)d_in[10];
  const float* wpos  = (const float*)d_in[11];
  const float* bpos  = (const float*)d_in[12];
  float* out = (float*)d_out;
  float* ws  = (float*)d_ws;

  // workspace layout (float slots)
  ushort* xb   = (ushort*)(ws + 0);             // 512KB region
  ushort* xtf  = (ushort*)(ws + 262144);        // 512KB region
  float*  w2   = ws + 524288;                   // 16384
  float*  b2   = ws + 540672;                   // 128
  int KS = 8;
  while (KS > 1 && (540800ull + (size_t)KS * 278528ull) * 4ull > ws_size) KS >>= 1;
  float*  lpart = ws + 540800;                  // KS*16384
  ushort* acct  = (ushort*)(ws + 540800 + (size_t)KS * 16384);  // KS*524288 bf16

  hipLaunchKernelGGL(k_prep,   dim3(256),      dim3(256),  0, stream, x, xb, xtf);
  hipLaunchKernelGGL(k_tiny2,  dim3(4),        dim3(1024), 0, stream,
                     xtf, wq, bq, wk, bk, wv, bv, gamma, wpos, bpos, w2, b2);
  hipLaunchKernelGGL(k_flash2, dim3(128 * KS), dim3(256),  0, stream,
                     xb, xtf, acct, lpart, KS);
  hipLaunchKernelGGL(k_cc,     dim3(16, 4),    dim3(256),  0, stream,
                     acct, lpart, x, beta, wch, bch, w2, b2, out, KS);
}

// Round 9
// 82.243 us; speedup vs baseline: 1.1832x; 1.1832x over previous
//
#include <hip/hip_runtime.h>
#include <cstddef>

// Shapes: B=4, H=W=D=16, C=32, N=4096, Dout=13; out (4,16,16,13,32) f32.

typedef float f32x4 __attribute__((ext_vector_type(4)));
typedef short s16x8 __attribute__((ext_vector_type(8)));

#define SQRT_LOG2E 1.2011224087864498f   // xb scaled so QK^T lands in exp2 domain
#define C2SHIFT    57.70780163555854f    // 40*log2(e)

// RNE f32->bf16 pack of two floats into one u32 (low = first arg). Proven R1-R8.
__device__ inline unsigned pk2(float a, float b) {
  union { float f; unsigned u; } ca, cb;
  ca.f = a; cb.f = b;
  unsigned ra = (ca.u + 0x7fffu + ((ca.u >> 16) & 1u)) >> 16;
  unsigned rb = (cb.u + 0x7fffu + ((cb.u >> 16) & 1u)) >> 16;
  return ra | (rb << 16);
}

// ---------------------------------------------------------------------------
// Kernel A: blocks 0..255 = prep (xb scaled bf16, xtf X^T A-frag tiles);
// blocks 256..259 = per-batch Gram (from raw x) + algebra -> folded w2/b2.
// The two groups are fully independent (gram reads x, not prep outputs).
// ---------------------------------------------------------------------------
__global__ __launch_bounds__(256) void k_prepalg(
    const float* __restrict__ x,
    const float* __restrict__ wq, const float* __restrict__ bq,
    const float* __restrict__ wk, const float* __restrict__ bk,
    const float* __restrict__ wv, const float* __restrict__ bv,
    const float* __restrict__ gamma,
    const float* __restrict__ wpos, const float* __restrict__ bpos,
    ushort* __restrict__ xb, ushort* __restrict__ xtf,
    float* __restrict__ w2, float* __restrict__ b2)
{
  int bx = blockIdx.x;
  int tid = threadIdx.x;
  if (bx < 256) {
    // ---- prep (proven R8 body) ----
    int t = bx * 256 + tid;                        // 0..65535
    const float4* xs = (const float4*)x;
    float4 v0 = xs[2 * t], v1 = xs[2 * t + 1];
    uint4 o;
    o.x = pk2(v0.x * SQRT_LOG2E, v0.y * SQRT_LOG2E);
    o.y = pk2(v0.z * SQRT_LOG2E, v0.w * SQRT_LOG2E);
    o.z = pk2(v1.x * SQRT_LOG2E, v1.y * SQRT_LOG2E);
    o.w = pk2(v1.z * SQRT_LOG2E, v1.w * SQRT_LOG2E);
    ((uint4*)xb)[t] = o;

    int b = t >> 14, r2 = t & 16383;
    int ktile = r2 >> 7, r3 = r2 & 127;
    int h = r3 >> 6, lane = r3 & 63;
    int g = lane >> 4, c = h * 16 + (lane & 15);
    const float* src = x + (((size_t)b * 4096 + ktile * 32 + 8 * g) * 32 + c);
    float w[8];
#pragma unroll
    for (int j = 0; j < 8; ++j) w[j] = src[(size_t)j * 32];
    uint4 u;
    u.x = pk2(w[0], w[1]); u.y = pk2(w[2], w[3]);
    u.z = pk2(w[4], w[5]); u.w = pk2(w[6], w[7]);
    ((uint4*)xtf)[(size_t)((b * 128 + ktile) * 2 + h) * 64 + lane] = u;
    return;
  }

  // ---- Gram + algebra for b = bx-256 ----
  __shared__ float G[1024], s[32], t1[1024], att[1024], M[1024], mvec[32];
  int b = bx - 256;
  int wid = tid >> 6, lane = tid & 63, g = lane >> 4, c16 = lane & 15;
  for (int i = tid; i < 1024; i += 256) G[i] = 0.f;
  if (tid < 32) s[tid] = 0.f;
  __syncthreads();

  f32x4 z = {0.f, 0.f, 0.f, 0.f};
  f32x4 G00 = z, G01 = z, G10 = z, G11 = z, s0 = z, s1 = z;
  s16x8 ones;
#pragma unroll
  for (int j = 0; j < 8; ++j) ones[j] = (short)0x3F80;
  for (int t = wid * 32; t < wid * 32 + 32; ++t) {
    s16x8 fr[2];
#pragma unroll
    for (int h = 0; h < 2; ++h) {
      const float* src = x + (((size_t)b * 4096 + t * 32 + 8 * g) * 32 + h * 16 + c16);
      float w[8];
#pragma unroll
      for (int j = 0; j < 8; ++j) w[j] = src[(size_t)j * 32];
      uint4 u = make_uint4(pk2(w[0], w[1]), pk2(w[2], w[3]),
                           pk2(w[4], w[5]), pk2(w[6], w[7]));
      fr[h] = __builtin_bit_cast(s16x8, u);
    }
    G00 = __builtin_amdgcn_mfma_f32_16x16x32_bf16(fr[0], fr[0], G00, 0, 0, 0);
    G01 = __builtin_amdgcn_mfma_f32_16x16x32_bf16(fr[0], fr[1], G01, 0, 0, 0);
    G10 = __builtin_amdgcn_mfma_f32_16x16x32_bf16(fr[1], fr[0], G10, 0, 0, 0);
    G11 = __builtin_amdgcn_mfma_f32_16x16x32_bf16(fr[1], fr[1], G11, 0, 0, 0);
    s0  = __builtin_amdgcn_mfma_f32_16x16x32_bf16(fr[0], ones, s0, 0, 0, 0);
    s1  = __builtin_amdgcn_mfma_f32_16x16x32_bf16(fr[1], ones, s1, 0, 0, 0);
  }
#pragma unroll
  for (int hr = 0; hr < 2; ++hr)
#pragma unroll
    for (int hc = 0; hc < 2; ++hc) {
      f32x4 v = hr ? (hc ? G11 : G10) : (hc ? G01 : G00);
#pragma unroll
      for (int r = 0; r < 4; ++r)
        atomicAdd(&G[(16 * hr + 4 * g + r) * 32 + 16 * hc + c16], v[r]);
    }
  if (c16 == 0) {
#pragma unroll
    for (int hr = 0; hr < 2; ++hr) {
      f32x4 v = hr ? s1 : s0;
#pragma unroll
      for (int r = 0; r < 4; ++r) atomicAdd(&s[16 * hr + 4 * g + r], v[r]);
    }
  }
  __syncthreads();

  // stage B at 256 threads: f = tid&31, c = (tid>>5) + 8*pass
  int f = tid & 31, cq = tid >> 5;
  for (int p = 0; p < 4; ++p) {
    int c = cq + 8 * p;
    float t = 0.f;
    for (int j = 0; j < 32; ++j) t = fmaf(G[c * 32 + j], wk[j * 32 + f], t);
    t1[c * 32 + f] = t;
  }
  __syncthreads();
  float swk = 0.f;
  for (int j = 0; j < 32; ++j) swk = fmaf(s[j], wk[j * 32 + f], swk);
  for (int p = 0; p < 4; ++p) {
    int c = cq + 8 * p;
    float swq = 0.f;
    for (int j = 0; j < 32; ++j) swq = fmaf(s[j], wq[j * 32 + c], swq);
    float e = 0.f;
    for (int i = 0; i < 32; ++i) e = fmaf(wq[i * 32 + c], t1[i * 32 + f], e);
    e += bq[c] * (swk + 4096.f * bk[f]) + swq * bk[f];
    float m_ = e;
    for (int off = 16; off; off >>= 1) m_ = fmaxf(m_, __shfl_xor(m_, off, 32));
    float pr = __expf(e - m_);
    float sum = pr;
    for (int off = 16; off; off >>= 1) sum += __shfl_xor(sum, off, 32);
    att[c * 32 + f] = pr / sum;
  }
  __syncthreads();
  for (int p = 0; p < 4; ++p) {
    int c = cq + 8 * p;
    float mm = 0.f;
    for (int j = 0; j < 32; ++j) mm = fmaf(wv[c * 32 + j], att[f * 32 + j], mm);
    M[c * 32 + f] = mm;
  }
  if (tid < 32) {
    float mv = 0.f;
    for (int j = 0; j < 32; ++j) mv = fmaf(bv[j], att[tid * 32 + j], mv);
    mvec[tid] = mv;
  }
  __syncthreads();
  float gam = gamma[0];
  for (int p = 0; p < 4; ++p) {
    int c = cq + 8 * p;
    for (int kd = 0; kd < 4; ++kd) {
      float acc = 0.f;
      for (int j = 0; j < 32; ++j)
        acc = fmaf(M[c * 32 + j], wpos[(kd * 32 + j) * 32 + f], acc);
      w2[((b * 4 + kd) * 32 + c) * 32 + f] = gam * acc + wpos[(kd * 32 + c) * 32 + f];
    }
  }
  if (tid < 32) {
    float acc = 0.f;
    for (int kd = 0; kd < 4; ++kd)
      for (int j = 0; j < 32; ++j)
        acc = fmaf(mvec[j], wpos[(kd * 32 + j) * 32 + tid], acc);
    b2[b * 32 + tid] = gam * acc + bpos[tid];
  }
}

// ---------------------------------------------------------------------------
// Kernel B: fully fused flash attention (KS=1) + combine + conv + output.
// grid (64 rowgroups, 4 b) x 256 thr; wave owns 16 q-rows; block owns 64 rows
// = 4 hw columns x all 16 d -> conv computed in-block from LDS ca.
// Register-only P path (key-row permutation), exp2 domain, ones-MFMA L.
// ---------------------------------------------------------------------------
__global__ __launch_bounds__(256) void k_fused(
    const ushort* __restrict__ xb, const ushort* __restrict__ xtf,
    const float* __restrict__ x, const float* __restrict__ beta,
    const float* __restrict__ wch, const float* __restrict__ bch,
    const float* __restrict__ w2, const float* __restrict__ b2,
    float* __restrict__ out)
{
  __shared__ float sS[64][32];                     // beta * attnout / L
  __shared__ float4 wcS[1024], wpS[1024];
  __shared__ float bcS[32], bpS[32];
  int rg = blockIdx.x, b = blockIdx.y, tid = threadIdx.x;
  for (int i = tid; i < 1024; i += 256) {
    wcS[i] = ((const float4*)wch)[i];
    wpS[i] = ((const float4*)(w2 + (size_t)b * 4096))[i];
  }
  if (tid < 32) { bcS[tid] = bch[tid]; bpS[tid] = b2[b * 32 + tid]; }

  int wid = tid >> 6, lane = tid & 63, g = lane >> 4, c16 = lane & 15;
  int qw = rg * 64 + wid * 16;
  const ushort* xbb = xb + ((size_t)b << 17);
  const ushort* xtb = xtf + (size_t)b * 131072;

  s16x8 qA = *(const s16x8*)(xbb + (qw + c16) * 32 + 8 * g);
  f32x4 z = {0.f, 0.f, 0.f, 0.f};
  f32x4 minit = {-C2SHIFT, -C2SHIFT, -C2SHIFT, -C2SHIFT};
  f32x4 oA0 = z, oA1 = z, lac = z;
  s16x8 ones;
#pragma unroll
  for (int j = 0; j < 8; ++j) ones[j] = (short)0x3F80;
  int kap = ((c16 >> 2) << 3) + (c16 & 3);         // kappa(c16)

  for (int kt = 0; kt < 4096; kt += 32) {
    const ushort* kr = xbb + (size_t)kt * 32;
    s16x8 kf0 = *(const s16x8*)(kr + (size_t)kap * 32 + 8 * g);
    s16x8 kf1 = *(const s16x8*)(kr + (size_t)(kap + 4) * 32 + 8 * g);
    const ushort* xt = xtb + (size_t)(kt >> 5) * 1024 + lane * 8;
    s16x8 a0 = *(const s16x8*)(xt);
    s16x8 a1 = *(const s16x8*)(xt + 512);

    f32x4 e0 = __builtin_amdgcn_mfma_f32_16x16x32_bf16(kf0, qA, minit, 0, 0, 0);
    f32x4 e1 = __builtin_amdgcn_mfma_f32_16x16x32_bf16(kf1, qA, minit, 0, 0, 0);
    f32x4 p0, p1;
#pragma unroll
    for (int r = 0; r < 4; ++r) {
      p0[r] = __builtin_amdgcn_exp2f(e0[r]);
      p1[r] = __builtin_amdgcn_exp2f(e1[r]);
    }
    uint4 uA = make_uint4(pk2(p0[0], p0[1]), pk2(p0[2], p0[3]),
                          pk2(p1[0], p1[1]), pk2(p1[2], p1[3]));
    s16x8 fp = __builtin_bit_cast(s16x8, uA);

    oA0 = __builtin_amdgcn_mfma_f32_16x16x32_bf16(a0, fp, oA0, 0, 0, 0);
    oA1 = __builtin_amdgcn_mfma_f32_16x16x32_bf16(a1, fp, oA1, 0, 0, 0);
    lac = __builtin_amdgcn_mfma_f32_16x16x32_bf16(ones, fp, lac, 0, 0, 0);
  }

  // lac[0] = L[q=c16] in every lane (all D rows of ones-MFMA are identical).
  float sc = beta[0] / lac[0];
  int rloc = wid * 16 + c16;
  f32x4 v0, v1;
#pragma unroll
  for (int r = 0; r < 4; ++r) { v0[r] = oA0[r] * sc; v1[r] = oA1[r] * sc; }
  *(f32x4*)&sS[rloc][4 * g] = v0;
  *(f32x4*)&sS[rloc][16 + 4 * g] = v1;
  __syncthreads();

  // conv3d(1,1,4) + relu both branches; ca = sS + x re-derived on the fly.
  if (tid < 208) {
    int row2 = tid >> 2, fq = tid & 3;             // 52 rows x 4 f-quarters
    int hw_l = row2 / 13, dout = row2 % 13;
    int rbase = hw_l * 16 + dout;
    size_t xrow = ((size_t)b * 4096 + (size_t)(rg * 4 + hw_l) * 16 + dout) * 32;
    float accC[8], accP[8];
#pragma unroll
    for (int j = 0; j < 8; ++j) { accC[j] = bcS[fq * 8 + j]; accP[j] = bpS[fq * 8 + j]; }
    for (int kd = 0; kd < 4; ++kd) {
      const float4* xr4 = (const float4*)(x + xrow + (size_t)kd * 32);
      const float* srow = sS[rbase + kd];
#pragma unroll
      for (int c4 = 0; c4 < 8; ++c4) {
        float4 xv = xr4[c4];
#pragma unroll
        for (int e = 0; e < 4; ++e) {
          float xve = (e == 0 ? xv.x : e == 1 ? xv.y : e == 2 ? xv.z : xv.w);
          float cve = srow[4 * c4 + e] + xve;      // ca = beta*o/L + x
          int wbase = (kd * 32 + 4 * c4 + e) * 8 + fq * 2;
          float4 w1a = wcS[wbase], w1b = wcS[wbase + 1];
          accC[0] = fmaf(cve, w1a.x, accC[0]);
          accC[1] = fmaf(cve, w1a.y, accC[1]);
          accC[2] = fmaf(cve, w1a.z, accC[2]);
          accC[3] = fmaf(cve, w1a.w, accC[3]);
          accC[4] = fmaf(cve, w1b.x, accC[4]);
          accC[5] = fmaf(cve, w1b.y, accC[5]);
          accC[6] = fmaf(cve, w1b.z, accC[6]);
          accC[7] = fmaf(cve, w1b.w, accC[7]);
          float4 w2a = wpS[wbase], w2b = wpS[wbase + 1];
          accP[0] = fmaf(xve, w2a.x, accP[0]);
          accP[1] = fmaf(xve, w2a.y, accP[1]);
          accP[2] = fmaf(xve, w2a.z, accP[2]);
          accP[3] = fmaf(xve, w2a.w, accP[3]);
          accP[4] = fmaf(xve, w2b.x, accP[4]);
          accP[5] = fmaf(xve, w2b.y, accP[5]);
          accP[6] = fmaf(xve, w2b.z, accP[6]);
          accP[7] = fmaf(xve, w2b.w, accP[7]);
        }
      }
    }
    int gid = b * 3328 + (rg * 4 + hw_l) * 13 + dout;
    float* orow = out + (size_t)gid * 32 + fq * 8;
    float4 o0, o1;
    o0.x = fmaxf(accC[0], 0.f) + fmaxf(accP[0], 0.f);
    o0.y = fmaxf(accC[1], 0.f) + fmaxf(accP[1], 0.f);
    o0.z = fmaxf(accC[2], 0.f) + fmaxf(accP[2], 0.f);
    o0.w = fmaxf(accC[3], 0.f) + fmaxf(accP[3], 0.f);
    o1.x = fmaxf(accC[4], 0.f) + fmaxf(accP[4], 0.f);
    o1.y = fmaxf(accC[5], 0.f) + fmaxf(accP[5], 0.f);
    o1.z = fmaxf(accC[6], 0.f) + fmaxf(accP[6], 0.f);
    o1.w = fmaxf(accC[7], 0.f) + fmaxf(accP[7], 0.f);
    ((float4*)orow)[0] = o0;
    ((float4*)orow)[1] = o1;
  }
}

extern "C" void kernel_launch(void* const* d_in, const int* in_sizes, int n_in,
                              void* d_out, int out_size, void* d_ws, size_t ws_size,
                              hipStream_t stream)
{
  const float* x     = (const float*)d_in[0];
  const float* beta  = (const float*)d_in[1];
  const float* wq    = (const float*)d_in[2];
  const float* bq    = (const float*)d_in[3];
  const float* wk    = (const float*)d_in[4];
  const float* bk    = (const float*)d_in[5];
  const float* wv    = (const float*)d_in[6];
  const float* bv    = (const float*)d_in[7];
  const float* gamma = (const float*)d_in[8];
  const float* wch   = (const float*)d_in[9];
  const float* bch   = (const float*)d_in[10];
  const float* wpos  = (const float*)d_in[11];
  const float* bpos  = (const float*)d_in[12];
  float* out = (float*)d_out;
  float* ws  = (float*)d_ws;

  ushort* xb  = (ushort*)(ws + 0);        // 512 KB
  ushort* xtf = (ushort*)(ws + 262144);   // 512 KB
  float*  w2  = ws + 524288;              // 64 KB
  float*  b2  = ws + 540672;              // 512 B

  hipLaunchKernelGGL(k_prepalg, dim3(260), dim3(256), 0, stream,
                     x, wq, bq, wk, bk, wv, bv, gamma, wpos, bpos,
                     xb, xtf, w2, b2);
  hipLaunchKernelGGL(k_fused, dim3(64, 4), dim3(256), 0, stream,
                     xb, xtf, x, beta, wch, bch, w2, b2, out);
}